// Round 3
// baseline (102.238 us; speedup 1.0000x reference)
//
#include <hip/hip_runtime.h>
#include <hip/hip_cooperative_groups.h>

namespace cg = cooperative_groups;

#define N_NODES_C 50000
#define N_EDGES_C 600000
#define DIM 128

// ---------------------------------------------------------------------------
// Fused: phase 1 (node projections, grid-stride) -> grid.sync() ->
//        phase 2 (edge gather-add, grid-stride).
//   P[n][c] = dot(h[n], W[c][0:128]) + b[c]
//   Q[n][c] = dot(h[n], W[c][128:256])
//   out[e][c] = P[src[e]][c] + Q[dst[e]][c]
// 16 lanes per node (4 nodes/wave), float4 h loads, W hoisted out of loop.
// 1024 blocks x 256 threads, <=128 VGPR -> all blocks co-resident (4/CU).
// ---------------------------------------------------------------------------
__global__ __launch_bounds__(256, 4) void fused_kernel(
    const float* __restrict__ h, const float* __restrict__ W,
    const float* __restrict__ b,
    const int* __restrict__ src, const int* __restrict__ dst,
    float* __restrict__ P, float* __restrict__ Q, float* __restrict__ out)
{
    const int tid   = blockIdx.x * blockDim.x + threadIdx.x;
    const int nthr  = gridDim.x * blockDim.x;
    const int lane  = threadIdx.x & 63;
    const int sub   = lane & 15;
    const int wave  = tid >> 6;
    const int nwave = nthr >> 6;

    // ---- Phase 1 ----
    // W fragments are uniform per lane-sub; load once (8 x float4 = 32 VGPR).
    const float4* Wu0 = reinterpret_cast<const float4*>(W + 0 * 2 * DIM);
    const float4* Wv0 = reinterpret_cast<const float4*>(W + 0 * 2 * DIM + DIM);
    const float4* Wu1 = reinterpret_cast<const float4*>(W + 1 * 2 * DIM);
    const float4* Wv1 = reinterpret_cast<const float4*>(W + 1 * 2 * DIM + DIM);
    const float4 u0a = Wu0[sub * 2], u0b = Wu0[sub * 2 + 1];
    const float4 v0a = Wv0[sub * 2], v0b = Wv0[sub * 2 + 1];
    const float4 u1a = Wu1[sub * 2], u1b = Wu1[sub * 2 + 1];
    const float4 v1a = Wv1[sub * 2], v1b = Wv1[sub * 2 + 1];
    const float b0 = b[0], b1 = b[1];

    for (int node = wave * 4 + (lane >> 4); node < N_NODES_C; node += nwave * 4) {
        const float4* hrow = reinterpret_cast<const float4*>(h + (size_t)node * DIM);
        const float4 a0 = hrow[sub * 2];
        const float4 a1 = hrow[sub * 2 + 1];

        float su0 = a0.x*u0a.x + a0.y*u0a.y + a0.z*u0a.z + a0.w*u0a.w
                  + a1.x*u0b.x + a1.y*u0b.y + a1.z*u0b.z + a1.w*u0b.w;
        float sv0 = a0.x*v0a.x + a0.y*v0a.y + a0.z*v0a.z + a0.w*v0a.w
                  + a1.x*v0b.x + a1.y*v0b.y + a1.z*v0b.z + a1.w*v0b.w;
        float su1 = a0.x*u1a.x + a0.y*u1a.y + a0.z*u1a.z + a0.w*u1a.w
                  + a1.x*u1b.x + a1.y*u1b.y + a1.z*u1b.z + a1.w*u1b.w;
        float sv1 = a0.x*v1a.x + a0.y*v1a.y + a0.z*v1a.z + a0.w*v1a.w
                  + a1.x*v1b.x + a1.y*v1b.y + a1.z*v1b.z + a1.w*v1b.w;

        #pragma unroll
        for (int off = 8; off > 0; off >>= 1) {
            su0 += __shfl_xor(su0, off, 64);
            su1 += __shfl_xor(su1, off, 64);
            sv0 += __shfl_xor(sv0, off, 64);
            sv1 += __shfl_xor(sv1, off, 64);
        }

        if (sub == 0) {
            *reinterpret_cast<float2*>(P + (size_t)node * 2) = make_float2(su0 + b0, su1 + b1);
            *reinterpret_cast<float2*>(Q + (size_t)node * 2) = make_float2(sv0, sv1);
        }
    }

    cg::this_grid().sync();

    // ---- Phase 2 ----
    const int npairs = N_EDGES_C / 2;
    for (int i = tid; i < npairs; i += nthr) {
        const int2 s = reinterpret_cast<const int2*>(src)[i];
        const int2 d = reinterpret_cast<const int2*>(dst)[i];

        const float2 p0 = *reinterpret_cast<const float2*>(P + (size_t)s.x * 2);
        const float2 q0 = *reinterpret_cast<const float2*>(Q + (size_t)d.x * 2);
        const float2 p1 = *reinterpret_cast<const float2*>(P + (size_t)s.y * 2);
        const float2 q1 = *reinterpret_cast<const float2*>(Q + (size_t)d.y * 2);

        float4 r;
        r.x = p0.x + q0.x;
        r.y = p0.y + q0.y;
        r.z = p1.x + q1.x;
        r.w = p1.y + q1.y;
        reinterpret_cast<float4*>(out)[i] = r;
    }
}

// --------------------- fallback: two-kernel path ---------------------------
__global__ __launch_bounds__(256) void node_proj_kernel(
    const float* __restrict__ h, const float* __restrict__ W,
    const float* __restrict__ b, float* __restrict__ P, float* __restrict__ Q)
{
    const int wave = blockIdx.x * (blockDim.x >> 6) + (threadIdx.x >> 6);
    const int lane = threadIdx.x & 63;
    const int sub  = lane & 15;
    const int node = wave * 4 + (lane >> 4);
    if (node >= N_NODES_C) return;

    const float4* hrow = reinterpret_cast<const float4*>(h + (size_t)node * DIM);
    const float4 a0 = hrow[sub * 2];
    const float4 a1 = hrow[sub * 2 + 1];

    const float4* Wu0 = reinterpret_cast<const float4*>(W + 0 * 2 * DIM);
    const float4* Wv0 = reinterpret_cast<const float4*>(W + 0 * 2 * DIM + DIM);
    const float4* Wu1 = reinterpret_cast<const float4*>(W + 1 * 2 * DIM);
    const float4* Wv1 = reinterpret_cast<const float4*>(W + 1 * 2 * DIM + DIM);
    const float4 u0a = Wu0[sub * 2], u0b = Wu0[sub * 2 + 1];
    const float4 v0a = Wv0[sub * 2], v0b = Wv0[sub * 2 + 1];
    const float4 u1a = Wu1[sub * 2], u1b = Wu1[sub * 2 + 1];
    const float4 v1a = Wv1[sub * 2], v1b = Wv1[sub * 2 + 1];

    float su0 = a0.x*u0a.x + a0.y*u0a.y + a0.z*u0a.z + a0.w*u0a.w
              + a1.x*u0b.x + a1.y*u0b.y + a1.z*u0b.z + a1.w*u0b.w;
    float sv0 = a0.x*v0a.x + a0.y*v0a.y + a0.z*v0a.z + a0.w*v0a.w
              + a1.x*v0b.x + a1.y*v0b.y + a1.z*v0b.z + a1.w*v0b.w;
    float su1 = a0.x*u1a.x + a0.y*u1a.y + a0.z*u1a.z + a0.w*u1a.w
              + a1.x*u1b.x + a1.y*u1b.y + a1.z*u1b.z + a1.w*u1b.w;
    float sv1 = a0.x*v1a.x + a0.y*v1a.y + a0.z*v1a.z + a0.w*v1a.w
              + a1.x*v1b.x + a1.y*v1b.y + a1.z*v1b.z + a1.w*v1b.w;

    #pragma unroll
    for (int off = 8; off > 0; off >>= 1) {
        su0 += __shfl_xor(su0, off, 64);
        su1 += __shfl_xor(su1, off, 64);
        sv0 += __shfl_xor(sv0, off, 64);
        sv1 += __shfl_xor(sv1, off, 64);
    }

    if (sub == 0) {
        *reinterpret_cast<float2*>(P + (size_t)node * 2) = make_float2(su0 + b[0], su1 + b[1]);
        *reinterpret_cast<float2*>(Q + (size_t)node * 2) = make_float2(sv0, sv1);
    }
}

__global__ __launch_bounds__(256) void edge_score_kernel(
    const int* __restrict__ src, const int* __restrict__ dst,
    const float* __restrict__ P, const float* __restrict__ Q,
    float* __restrict__ out)
{
    const int npairs = N_EDGES_C / 2;
    const int i = blockIdx.x * blockDim.x + threadIdx.x;
    if (i >= npairs) return;

    const int2 s = reinterpret_cast<const int2*>(src)[i];
    const int2 d = reinterpret_cast<const int2*>(dst)[i];

    const float2 p0 = *reinterpret_cast<const float2*>(P + (size_t)s.x * 2);
    const float2 q0 = *reinterpret_cast<const float2*>(Q + (size_t)d.x * 2);
    const float2 p1 = *reinterpret_cast<const float2*>(P + (size_t)s.y * 2);
    const float2 q1 = *reinterpret_cast<const float2*>(Q + (size_t)d.y * 2);

    float4 r;
    r.x = p0.x + q0.x;
    r.y = p0.y + q0.y;
    r.z = p1.x + q1.x;
    r.w = p1.y + q1.y;
    reinterpret_cast<float4*>(out)[i] = r;
}

extern "C" void kernel_launch(void* const* d_in, const int* in_sizes, int n_in,
                              void* d_out, int out_size, void* d_ws, size_t ws_size,
                              hipStream_t stream) {
    const float* h   = (const float*)d_in[0];
    const float* W   = (const float*)d_in[1];
    const float* b   = (const float*)d_in[2];
    const int*   src = (const int*)d_in[3];
    const int*   dst = (const int*)d_in[4];
    float* out = (float*)d_out;

    float* P = (float*)d_ws;
    float* Q = P + (size_t)N_NODES_C * 2;

    // Cooperative fused launch: 1024 blocks x 256 threads (4 blocks/CU, all
    // co-resident given __launch_bounds__(256,4) caps VGPR at 128).
    void* args[] = {(void*)&h, (void*)&W, (void*)&b, (void*)&src, (void*)&dst,
                    (void*)&P, (void*)&Q, (void*)&out};
    hipError_t err = hipLaunchCooperativeKernel(
        reinterpret_cast<const void*>(fused_kernel),
        dim3(1024), dim3(256), args, 0, stream);

    if (err != hipSuccess) {
        // Fallback: two dependent kernels on the stream.
        const int grid1 = (N_NODES_C + 15) / 16;  // 16 nodes per 256-thr block
        node_proj_kernel<<<grid1, 256, 0, stream>>>(h, W, b, P, Q);
        const int npairs = N_EDGES_C / 2;
        const int grid2 = (npairs + 255) / 256;
        edge_score_kernel<<<grid2, 256, 0, stream>>>(src, dst, P, Q, out);
    }
}

// Round 4
// 18.868 us; speedup vs baseline: 5.4186x; 5.4186x over previous
//
#include <hip/hip_runtime.h>

#define N_NODES_C 50000
#define N_EDGES_C 600000
#define DIM 128

// ---------------------------------------------------------------------------
// Phase 1: per-node projections, 16 lanes per node-pair group, 2 nodes per
// group (8 nodes/wave, 32 nodes per 256-thread block).
//   P[n][c] = dot(h[n], W[c][0:128]) + b[c]
//   Q[n][c] = dot(h[n], W[c][128:256])
// Each lane loads 2x float4 from each of two consecutive rows (64 B in
// flight), giving 4 independent global loads per thread. Adjacent nodes
// reduce into the same lane -> single float4 store to P and to Q.
// ---------------------------------------------------------------------------
__global__ __launch_bounds__(256) void node_proj_kernel(
    const float* __restrict__ h, const float* __restrict__ W,
    const float* __restrict__ b, float* __restrict__ P, float* __restrict__ Q)
{
    const int wave = blockIdx.x * 4 + (threadIdx.x >> 6);
    const int lane = threadIdx.x & 63;
    const int sub  = lane & 15;
    const int node0 = wave * 8 + (lane >> 4) * 2;   // even; node0+1 valid (N even)
    if (node0 >= N_NODES_C) return;

    // W fragments (same 128 B per lane for every block -> L1-hot)
    const float4* Wu0 = reinterpret_cast<const float4*>(W + 0 * 2 * DIM);
    const float4* Wv0 = reinterpret_cast<const float4*>(W + 0 * 2 * DIM + DIM);
    const float4* Wu1 = reinterpret_cast<const float4*>(W + 1 * 2 * DIM);
    const float4* Wv1 = reinterpret_cast<const float4*>(W + 1 * 2 * DIM + DIM);
    const float4 u0a = Wu0[sub * 2], u0b = Wu0[sub * 2 + 1];
    const float4 v0a = Wv0[sub * 2], v0b = Wv0[sub * 2 + 1];
    const float4 u1a = Wu1[sub * 2], u1b = Wu1[sub * 2 + 1];
    const float4 v1a = Wv1[sub * 2], v1b = Wv1[sub * 2 + 1];

    // Two rows, 4 independent 16 B loads issued back-to-back
    const float4* r0 = reinterpret_cast<const float4*>(h + (size_t)node0 * DIM);
    const float4* r1 = reinterpret_cast<const float4*>(h + (size_t)(node0 + 1) * DIM);
    const float4 a0 = r0[sub * 2];
    const float4 a1 = r0[sub * 2 + 1];
    const float4 c0 = r1[sub * 2];
    const float4 c1 = r1[sub * 2 + 1];

    float su0_0 = a0.x*u0a.x + a0.y*u0a.y + a0.z*u0a.z + a0.w*u0a.w
                + a1.x*u0b.x + a1.y*u0b.y + a1.z*u0b.z + a1.w*u0b.w;
    float su1_0 = a0.x*u1a.x + a0.y*u1a.y + a0.z*u1a.z + a0.w*u1a.w
                + a1.x*u1b.x + a1.y*u1b.y + a1.z*u1b.z + a1.w*u1b.w;
    float sv0_0 = a0.x*v0a.x + a0.y*v0a.y + a0.z*v0a.z + a0.w*v0a.w
                + a1.x*v0b.x + a1.y*v0b.y + a1.z*v0b.z + a1.w*v0b.w;
    float sv1_0 = a0.x*v1a.x + a0.y*v1a.y + a0.z*v1a.z + a0.w*v1a.w
                + a1.x*v1b.x + a1.y*v1b.y + a1.z*v1b.z + a1.w*v1b.w;

    float su0_1 = c0.x*u0a.x + c0.y*u0a.y + c0.z*u0a.z + c0.w*u0a.w
                + c1.x*u0b.x + c1.y*u0b.y + c1.z*u0b.z + c1.w*u0b.w;
    float su1_1 = c0.x*u1a.x + c0.y*u1a.y + c0.z*u1a.z + c0.w*u1a.w
                + c1.x*u1b.x + c1.y*u1b.y + c1.z*u1b.z + c1.w*u1b.w;
    float sv0_1 = c0.x*v0a.x + c0.y*v0a.y + c0.z*v0a.z + c0.w*v0a.w
                + c1.x*v0b.x + c1.y*v0b.y + c1.z*v0b.z + c1.w*v0b.w;
    float sv1_1 = c0.x*v1a.x + c0.y*v1a.y + c0.z*v1a.z + c0.w*v1a.w
                + c1.x*v1b.x + c1.y*v1b.y + c1.z*v1b.z + c1.w*v1b.w;

    #pragma unroll
    for (int off = 8; off > 0; off >>= 1) {
        su0_0 += __shfl_xor(su0_0, off, 64);
        su1_0 += __shfl_xor(su1_0, off, 64);
        sv0_0 += __shfl_xor(sv0_0, off, 64);
        sv1_0 += __shfl_xor(sv1_0, off, 64);
        su0_1 += __shfl_xor(su0_1, off, 64);
        su1_1 += __shfl_xor(su1_1, off, 64);
        sv0_1 += __shfl_xor(sv0_1, off, 64);
        sv1_1 += __shfl_xor(sv1_1, off, 64);
    }

    if (sub == 0) {
        const float b0 = b[0], b1 = b[1];
        *reinterpret_cast<float4*>(P + (size_t)node0 * 2) =
            make_float4(su0_0 + b0, su1_0 + b1, su0_1 + b0, su1_1 + b1);
        *reinterpret_cast<float4*>(Q + (size_t)node0 * 2) =
            make_float4(sv0_0, sv1_0, sv0_1, sv1_1);
    }
}

// ---------------------------------------------------------------------------
// Phase 2: per-edge gather-add, 4 edges per thread.
// int4 index loads, 8 independent 8 B gathers in flight (P/Q = 800 KB,
// L2-resident), two coalesced float4 stores.
// ---------------------------------------------------------------------------
__global__ __launch_bounds__(256) void edge_score_kernel(
    const int* __restrict__ src, const int* __restrict__ dst,
    const float* __restrict__ P, const float* __restrict__ Q,
    float* __restrict__ out)
{
    const int nquads = N_EDGES_C / 4;   // 150000
    const int i = blockIdx.x * blockDim.x + threadIdx.x;
    if (i >= nquads) return;

    const int4 s = reinterpret_cast<const int4*>(src)[i];
    const int4 d = reinterpret_cast<const int4*>(dst)[i];

    const float2 p0 = *reinterpret_cast<const float2*>(P + (size_t)s.x * 2);
    const float2 p1 = *reinterpret_cast<const float2*>(P + (size_t)s.y * 2);
    const float2 p2 = *reinterpret_cast<const float2*>(P + (size_t)s.z * 2);
    const float2 p3 = *reinterpret_cast<const float2*>(P + (size_t)s.w * 2);
    const float2 q0 = *reinterpret_cast<const float2*>(Q + (size_t)d.x * 2);
    const float2 q1 = *reinterpret_cast<const float2*>(Q + (size_t)d.y * 2);
    const float2 q2 = *reinterpret_cast<const float2*>(Q + (size_t)d.z * 2);
    const float2 q3 = *reinterpret_cast<const float2*>(Q + (size_t)d.w * 2);

    float4 r0, r1;
    r0.x = p0.x + q0.x;  r0.y = p0.y + q0.y;
    r0.z = p1.x + q1.x;  r0.w = p1.y + q1.y;
    r1.x = p2.x + q2.x;  r1.y = p2.y + q2.y;
    r1.z = p3.x + q3.x;  r1.w = p3.y + q3.y;

    float4* o = reinterpret_cast<float4*>(out) + (size_t)i * 2;
    o[0] = r0;
    o[1] = r1;
}

extern "C" void kernel_launch(void* const* d_in, const int* in_sizes, int n_in,
                              void* d_out, int out_size, void* d_ws, size_t ws_size,
                              hipStream_t stream) {
    const float* h   = (const float*)d_in[0];
    const float* W   = (const float*)d_in[1];
    const float* b   = (const float*)d_in[2];
    const int*   src = (const int*)d_in[3];
    const int*   dst = (const int*)d_in[4];
    float* out = (float*)d_out;

    float* P = (float*)d_ws;
    float* Q = P + (size_t)N_NODES_C * 2;

    // Phase 1: 32 nodes per 256-thread block (4 waves x 8 nodes)
    const int grid1 = (N_NODES_C + 31) / 32;                 // 1563
    node_proj_kernel<<<grid1, 256, 0, stream>>>(h, W, b, P, Q);

    // Phase 2: 4 edges per thread
    const int grid2 = (N_EDGES_C / 4 + 255) / 256;           // 586
    edge_score_kernel<<<grid2, 256, 0, stream>>>(src, dst, P, Q, out);
}